// Round 5
// baseline (387.375 us; speedup 1.0000x reference)
//
#include <hip/hip_runtime.h>

// GCN: h = relu(Ahat (xW) + b); g = meanpool(h); out = relu(g W1 + b1) W2 + b2
// R5: R4 with the Abuf double-buffer write offset fixed (1024 uint4 per half,
//     not 2048 — 2048 aliased Bbuf[0] and left A buf1 stale).

typedef short s16x8 __attribute__((ext_vector_type(8)));
typedef unsigned short u16x8 __attribute__((ext_vector_type(8)));
typedef float f32x4 __attribute__((ext_vector_type(4)));

static constexpr int NN  = 50000;   // nodes
static constexpr int NE  = 800000;  // edges
static constexpr int KIN = 512;     // input feature dim
static constexpr int HID = 256;     // hidden dim
static constexpr int NG  = 128;     // graphs
static constexpr int NB  = (NN + 255) / 256;   // scan blocks = 196

__device__ __forceinline__ unsigned short f2bf(float f) {
  unsigned u = __float_as_uint(f);
  u += 0x7fffu + ((u >> 16) & 1u);   // RNE
  return (unsigned short)(u >> 16);
}

__device__ __forceinline__ unsigned cvtpk(float lo, float hi) {
  unsigned r;
  asm("v_cvt_pk_bf16_f32 %0, %1, %2" : "=v"(r) : "v"(lo), "v"(hi));
  return r;  // low16 = bf16(lo), high16 = bf16(hi)
}

__device__ __forceinline__ f32x4 bf4_to_f32(uint2 u) {
  f32x4 r;
  r[0] = __uint_as_float(u.x << 16);
  r[1] = __uint_as_float(u.x & 0xffff0000u);
  r[2] = __uint_as_float(u.y << 16);
  r[3] = __uint_as_float(u.y & 0xffff0000u);
  return r;
}

__device__ __forceinline__ void glds16(const void* g, void* l) {
  __builtin_amdgcn_global_load_lds(
      (const __attribute__((address_space(1))) void*)g,
      (__attribute__((address_space(3))) void*)l, 16, 0, 0);
}

// ---- W [512,256] fp32 -> Wt [256,512] bf16 (transposed: B-fragments contiguous in k)
__global__ void k_wt(const float* __restrict__ W, unsigned short* __restrict__ wt) {
  int idx = blockIdx.x * 256 + threadIdx.x;     // 131072 total
  int k = idx >> 8, n = idx & 255;
  wt[n * KIN + k] = f2bf(W[idx]);
}

// ---- incoming-degree histogram over dst
__global__ void k_deg(const int* __restrict__ dst, int* __restrict__ cnt) {
  int e = blockIdx.x * 256 + threadIdx.x;
  if (e < NE) atomicAdd(&cnt[dst[e]], 1);
}

// ---- per-block sums for scan + fused dinv
__global__ __launch_bounds__(256) void k_scan1(const int* __restrict__ cnt,
                                               int* __restrict__ bsum,
                                               float* __restrict__ dinv) {
  __shared__ int s[256];
  const int t = threadIdx.x;
  const int i = blockIdx.x * 256 + t;
  int v = (i < NN) ? cnt[i] : 0;
  if (i < NN) dinv[i] = rsqrtf((float)v + 1.0f);
  s[t] = v;
  __syncthreads();
  for (int off = 128; off > 0; off >>= 1) {
    if (t < off) s[t] += s[t + off];
    __syncthreads();
  }
  if (t == 0) bsum[blockIdx.x] = s[0];
}

__global__ __launch_bounds__(256) void k_scan2(const int* __restrict__ bsum,
                                               int* __restrict__ boff,
                                               int* __restrict__ rowptr) {
  __shared__ int sa[256], sb[256];
  const int t = threadIdx.x;
  int v = (t < NB) ? bsum[t] : 0;
  sa[t] = v;
  __syncthreads();
  int* rd = sa; int* wr = sb;
  for (int off = 1; off < 256; off <<= 1) {
    int u = rd[t];
    if (t >= off) u += rd[t - off];
    wr[t] = u;
    __syncthreads();
    int* tmp = rd; rd = wr; wr = tmp;
  }
  if (t < NB) boff[t] = rd[t] - v;     // exclusive
  if (t == 255) rowptr[NN] = rd[255];  // total = NE
}

__global__ __launch_bounds__(256) void k_scan3(const int* __restrict__ cnt,
                                               const int* __restrict__ boff,
                                               int* __restrict__ rowptr) {
  __shared__ int sa[256], sb[256];
  const int t = threadIdx.x;
  const int i = blockIdx.x * 256 + t;
  int v = (i < NN) ? cnt[i] : 0;
  sa[t] = v;
  __syncthreads();
  int* rd = sa; int* wr = sb;
  for (int off = 1; off < 256; off <<= 1) {
    int u = rd[t];
    if (t >= off) u += rd[t - off];
    wr[t] = u;
    __syncthreads();
    int* tmp = rd; rd = wr; wr = tmp;
  }
  if (i < NN) rowptr[i] = rd[t] - v + boff[blockIdx.x];
}

// ---- scatter edges into CSR-by-dst: col[...] = src
__global__ void k_scatter(const int* __restrict__ dst, const int* __restrict__ src,
                          const int* __restrict__ rowptr, int* __restrict__ fill,
                          int* __restrict__ col) {
  int e = blockIdx.x * 256 + threadIdx.x;
  if (e >= NE) return;
  int d = dst[e];
  int pos = rowptr[d] + atomicAdd(&fill[d], 1);
  col[pos] = src[e];
}

// ---- hs = (x @ W) * dinv[row] -> bf16.  BM=128, BN=128, BK=64, 4 waves (2x2).
// Depth-1 prefetch: issue A(reg)+B(glds) loads for t+1, compute t, then cvt+write A.
// LDS: A,B bf16 [2][128][64], slot s of row r holds global chunk s^(r&7).
__global__ __launch_bounds__(256) void k_gemm(const float* __restrict__ x,
                                              const unsigned short* __restrict__ wt,
                                              const float* __restrict__ dinv,
                                              unsigned short* __restrict__ hs) {
  __shared__ unsigned short Abuf[2 * 128 * 64];   // 32 KB; half = 8192 shorts = 1024 uint4
  __shared__ unsigned short Bbuf[2 * 128 * 64];   // 32 KB
  const int tid  = threadIdx.x;
  const int lane = tid & 63;
  const int w    = tid >> 6;
  const int wm = w >> 1, wn = w & 1;
  const int bm = (int)blockIdx.x >> 1, bn = (int)blockIdx.x & 1;
  const int m0 = bm * 128, n0 = bn * 128;
  const int l15 = lane & 15, l4 = lane >> 4;
  const int msw = l15 & 7;

  // A staging (reg): 2 thr/row, each 32 f32 (8 x dwordx4); row=tid>>1, half=tid&1
  const int arow = tid >> 1, ahalf = tid & 1;
  int gar = m0 + arow; if (gar > NN - 1) gar = NN - 1;
  const float* aptr = x + (size_t)gar * KIN + ahalf * 32;
  // B staging (glds): 4 issues x 32 rows; lane -> row (lane>>3), slot lane&7
  const int brl = lane >> 3;
  const int bcs = (lane & 7) ^ brl;                      // source chunk (8 bf16 units)
  const size_t bglane = (size_t)(w * 8 + brl) * KIN + bcs * 8;

  f32x4 acc[4][4];
  #pragma unroll
  for (int i = 0; i < 4; ++i)
    #pragma unroll
    for (int j = 0; j < 4; ++j) acc[i][j] = f32x4{0.f, 0.f, 0.f, 0.f};

  f32x4 areg[8];
  const unsigned short* wbase = wt + (size_t)n0 * KIN;

  // ---- prologue: stage t=0 into buf 0
  #pragma unroll
  for (int c = 0; c < 8; ++c) areg[c] = *(const f32x4*)(aptr + c * 4);
  #pragma unroll
  for (int i = 0; i < 4; ++i)
    glds16(wbase + (size_t)i * 32 * KIN + bglane, &Bbuf[(i * 32 + w * 8) * 64]);
  {
    unsigned pk[16];
    #pragma unroll
    for (int c = 0; c < 8; ++c) {
      pk[2 * c]     = cvtpk(areg[c][0], areg[c][1]);
      pk[2 * c + 1] = cvtpk(areg[c][2], areg[c][3]);
    }
    #pragma unroll
    for (int j = 0; j < 4; ++j) {
      const int slot = (ahalf * 4 + j) ^ (arow & 7);
      ((uint4*)Abuf)[arow * 8 + slot] = uint4{pk[4*j], pk[4*j+1], pk[4*j+2], pk[4*j+3]};
    }
  }
  __syncthreads();

  for (int t = 0; t < 8; ++t) {
    const int cur = t & 1;
    const int kb_next = (t + 1) * 64;
    if (t < 7) {   // issue prefetch for t+1
      #pragma unroll
      for (int c = 0; c < 8; ++c) areg[c] = *(const f32x4*)(aptr + kb_next + c * 4);
      #pragma unroll
      for (int i = 0; i < 4; ++i)
        glds16(wbase + (size_t)i * 32 * KIN + kb_next + bglane,
               &Bbuf[(cur ^ 1) * 8192 + (i * 32 + w * 8) * 64]);
    }
    // compute on buf[cur]
    const unsigned short* Ab = Abuf + cur * 8192;
    const unsigned short* Bb = Bbuf + cur * 8192;
    #pragma unroll
    for (int ks = 0; ks < 2; ++ks) {
      s16x8 af[4], bfr[4];
      #pragma unroll
      for (int i = 0; i < 4; ++i) {
        const int r = wm * 64 + i * 16 + l15;
        af[i] = *(const s16x8*)(Ab + r * 64 + ((ks * 4 + l4) ^ msw) * 8);
      }
      #pragma unroll
      for (int j = 0; j < 4; ++j) {
        const int r = wn * 64 + j * 16 + l15;
        bfr[j] = *(const s16x8*)(Bb + r * 64 + ((ks * 4 + l4) ^ msw) * 8);
      }
      #pragma unroll
      for (int i = 0; i < 4; ++i)
        #pragma unroll
        for (int j = 0; j < 4; ++j)
          acc[i][j] = __builtin_amdgcn_mfma_f32_16x16x32_bf16(af[i], bfr[j], acc[i][j], 0, 0, 0);
    }
    if (t < 7) {   // cvt + write A for t+1 (compiler inserts the vmcnt wait on areg)
      unsigned pk[16];
      #pragma unroll
      for (int c = 0; c < 8; ++c) {
        pk[2 * c]     = cvtpk(areg[c][0], areg[c][1]);
        pk[2 * c + 1] = cvtpk(areg[c][2], areg[c][3]);
      }
      #pragma unroll
      for (int j = 0; j < 4; ++j) {
        const int slot = (ahalf * 4 + j) ^ (arow & 7);
        ((uint4*)Abuf)[(cur ^ 1) * 1024 + arow * 8 + slot] =
            uint4{pk[4*j], pk[4*j+1], pk[4*j+2], pk[4*j+3]};
      }
    }
    __syncthreads();
  }

  // epilogue: hs[row, col] = bf16(acc * dinv[row]); C/D: col=lane&15, row=(lane>>4)*4+r
  #pragma unroll
  for (int i = 0; i < 4; ++i)
    #pragma unroll
    for (int r = 0; r < 4; ++r) {
      const int gr = m0 + wm * 64 + i * 16 + l4 * 4 + r;
      if (gr < NN) {
        const float sc = dinv[gr];
        #pragma unroll
        for (int j = 0; j < 4; ++j)
          hs[(size_t)gr * HID + n0 + wn * 64 + j * 16 + l15] = f2bf(acc[i][j][r] * sc);
      }
    }
}

// ---- aggregate: h2[n] = relu( dinv[n]*(hs[n] + sum_{s in N(n)} hs[s]) + b ), bf16 out
// one wave per node; two half-waves alternate edges, 4 gathers in flight each
__global__ __launch_bounds__(256) void k_agg(const unsigned short* __restrict__ hs,
                                             const int* __restrict__ rowptr,
                                             const int* __restrict__ col,
                                             const float* __restrict__ dinv,
                                             const float* __restrict__ bias,
                                             unsigned short* __restrict__ h2) {
  const int n = blockIdx.x * 4 + (threadIdx.x >> 6);
  const int lane = threadIdx.x & 63;
  const int half = lane >> 5, q = lane & 31;
  const uint4* hp = (const uint4*)hs;               // 32 uint4 per row
  f32x4 a0 = {0.f,0.f,0.f,0.f}, a1 = {0.f,0.f,0.f,0.f};
  if (half == 0) {                                  // self term once
    uint4 v = hp[(size_t)n * 32 + q];
    a0 += bf4_to_f32(uint2{v.x, v.y}); a1 += bf4_to_f32(uint2{v.z, v.w});
  }
  const int s_ = rowptr[n], e_ = rowptr[n + 1];
  int j = s_ + half;
  for (; j + 6 < e_; j += 8) {                      // 4 edges in flight per half-wave
    int s0 = col[j], s1 = col[j + 2], s2 = col[j + 4], s3 = col[j + 6];
    uint4 v0 = hp[(size_t)s0 * 32 + q];
    uint4 v1 = hp[(size_t)s1 * 32 + q];
    uint4 v2 = hp[(size_t)s2 * 32 + q];
    uint4 v3 = hp[(size_t)s3 * 32 + q];
    a0 += bf4_to_f32(uint2{v0.x, v0.y}); a1 += bf4_to_f32(uint2{v0.z, v0.w});
    a0 += bf4_to_f32(uint2{v1.x, v1.y}); a1 += bf4_to_f32(uint2{v1.z, v1.w});
    a0 += bf4_to_f32(uint2{v2.x, v2.y}); a1 += bf4_to_f32(uint2{v2.z, v2.w});
    a0 += bf4_to_f32(uint2{v3.x, v3.y}); a1 += bf4_to_f32(uint2{v3.z, v3.w});
  }
  for (; j < e_; j += 2) {
    uint4 v = hp[(size_t)col[j] * 32 + q];
    a0 += bf4_to_f32(uint2{v.x, v.y}); a1 += bf4_to_f32(uint2{v.z, v.w});
  }
  #pragma unroll
  for (int c = 0; c < 4; ++c) {                     // combine halves
    a0[c] += __shfl_xor(a0[c], 32);
    a1[c] += __shfl_xor(a1[c], 32);
  }
  if (half == 0) {
    const float dn = dinv[n];
    f32x4 b0 = *(const f32x4*)(bias + q * 8);
    f32x4 b1 = *(const f32x4*)(bias + q * 8 + 4);
    float r0 = fmaxf(a0[0]*dn + b0[0], 0.f), r1 = fmaxf(a0[1]*dn + b0[1], 0.f);
    float r2 = fmaxf(a0[2]*dn + b0[2], 0.f), r3 = fmaxf(a0[3]*dn + b0[3], 0.f);
    float r4 = fmaxf(a1[0]*dn + b1[0], 0.f), r5 = fmaxf(a1[1]*dn + b1[1], 0.f);
    float r6 = fmaxf(a1[2]*dn + b1[2], 0.f), r7 = fmaxf(a1[3]*dn + b1[3], 0.f);
    uint4 o;
    o.x = cvtpk(r0, r1); o.y = cvtpk(r2, r3); o.z = cvtpk(r4, r5); o.w = cvtpk(r6, r7);
    ((uint4*)h2)[(size_t)n * 32 + q] = o;
  }
}

// ---- fused mean-pool (batch sorted -> binary search) + 2-layer MLP
__global__ __launch_bounds__(1024) void k_pool(const unsigned short* __restrict__ h2,
                                               const int* __restrict__ batch,
                                               const float* __restrict__ W1,
                                               const float* __restrict__ b1,
                                               const float* __restrict__ W2,
                                               const float* __restrict__ b2,
                                               float* __restrict__ out) {
  __shared__ f32x4 gp[16][64];
  __shared__ float gs[256];
  __shared__ float a1s[16];
  const int gi = blockIdx.x;
  const int tid = threadIdx.x;
  const int c4 = tid & 63, q = tid >> 6;            // 16 row-groups x 64 col-chunks(4)
  int lo = 0, hi = NN;
  while (lo < hi) { int mid = (lo + hi) >> 1; if (batch[mid] < gi) lo = mid + 1; else hi = mid; }
  const int s_ = lo;
  hi = NN;
  while (lo < hi) { int mid = (lo + hi) >> 1; if (batch[mid] < gi + 1) lo = mid + 1; else hi = mid; }
  const int e_ = lo;
  f32x4 sum = {0.f,0.f,0.f,0.f};
  for (int n = s_ + q; n < e_; n += 16)
    sum += bf4_to_f32(*(const uint2*)(h2 + (size_t)n * HID + c4 * 4));
  gp[q][c4] = sum;
  __syncthreads();
  if (tid < 64) {
    f32x4 tot = gp[0][tid];
    #pragma unroll
    for (int g = 1; g < 16; ++g) tot += gp[g][tid];
    const float inv = 1.0f / fmaxf((float)(e_ - s_), 1.0f);
    gs[tid*4+0] = tot[0]*inv; gs[tid*4+1] = tot[1]*inv;
    gs[tid*4+2] = tot[2]*inv; gs[tid*4+3] = tot[3]*inv;
  }
  __syncthreads();
  if (tid < 16) {
    float acc = b1[tid];
    #pragma unroll 4
    for (int k = 0; k < 256; ++k) acc += gs[k] * W1[k * 16 + tid];
    a1s[tid] = fmaxf(acc, 0.0f);
  }
  __syncthreads();
  if (tid < 10) {
    float acc = b2[tid];
    #pragma unroll
    for (int k = 0; k < 16; ++k) acc += a1s[k] * W2[k * 10 + tid];
    out[gi * 10 + tid] = acc;
  }
}

extern "C" void kernel_launch(void* const* d_in, const int* in_sizes, int n_in,
                              void* d_out, int out_size, void* d_ws, size_t ws_size,
                              hipStream_t stream) {
  const float* x     = (const float*)d_in[0];
  const int*   ei    = (const int*)d_in[1];      // [2,E]: src then dst
  const int*   batch = (const int*)d_in[2];
  const float* W     = (const float*)d_in[3];
  const float* b     = (const float*)d_in[4];
  const float* W1    = (const float*)d_in[5];
  const float* b1    = (const float*)d_in[6];
  const float* W2    = (const float*)d_in[7];
  const float* b2    = (const float*)d_in[8];
  float* out = (float*)d_out;
  char* ws = (char*)d_ws;

  size_t o = 0;
  auto al = [&](size_t bytes) { size_t r = o; o = (o + bytes + 255) & ~(size_t)255; return r; };
  unsigned short* wt = (unsigned short*)(ws + al((size_t)KIN * HID * 2));
  float* dinv        = (float*)(ws + al((size_t)NN * 4));
  int*   cnt         = (int*)(ws + al((size_t)NN * 4));
  int*   fill        = (int*)(ws + al((size_t)NN * 4));
  int*   rowptr      = (int*)(ws + al((size_t)(NN + 1) * 4));
  int*   col         = (int*)(ws + al((size_t)NE * 4));
  int*   bsum        = (int*)(ws + al((size_t)256 * 4));
  int*   boff        = (int*)(ws + al((size_t)256 * 4));
  unsigned short* hs = (unsigned short*)(ws + al((size_t)NN * HID * 2));
  unsigned short* h2 = (unsigned short*)(ws + al((size_t)NN * HID * 2));

  const int* src = ei;
  const int* dst = ei + NE;

  // zero cnt + fill (adjacent region)
  hipMemsetAsync(cnt, 0, (size_t)((char*)fill - (char*)cnt) + (size_t)NN * 4, stream);

  k_wt     <<<(KIN * HID) / 256, 256, 0, stream>>>(W, wt);
  k_deg    <<<(NE + 255) / 256, 256, 0, stream>>>(dst, cnt);
  k_scan1  <<<NB, 256, 0, stream>>>(cnt, bsum, dinv);
  k_scan2  <<<1, 256, 0, stream>>>(bsum, boff, rowptr);
  k_scan3  <<<NB, 256, 0, stream>>>(cnt, boff, rowptr);
  k_scatter<<<(NE + 255) / 256, 256, 0, stream>>>(dst, src, rowptr, fill, col);
  k_gemm   <<<((NN + 127) / 128) * 2, 256, 0, stream>>>(x, wt, dinv, hs);
  k_agg    <<<NN / 4, 256, 0, stream>>>(hs, rowptr, col, dinv, b, h2);
  k_pool   <<<NG, 1024, 0, stream>>>(h2, batch, W1, b1, W2, b2, out);
}